// Round 6
// baseline (5462.926 us; speedup 1.0000x reference)
//
#include <hip/hip_runtime.h>
#include <hip/hip_bf16.h>
#include <cfloat>
#include <cstddef>

#define BB 16
#define NN 2048
#define KNN 30

using bf16 = __hip_bfloat16;

// ---- static device scratch ----
constexpr size_t XT_O  = 0;
constexpr size_t NRM_O = XT_O  + (size_t)BB*64*NN;
constexpr size_t A_O   = NRM_O + (size_t)BB*NN;
constexpr size_t U_O   = A_O   + (size_t)BB*NN*64;
constexpr size_t H_O   = U_O   + (size_t)BB*NN*64;
constexpr size_t WS_F  = H_O   + (size_t)BB*NN*192;   // 12,615,680 floats = 50.5 MB
constexpr size_t H1_O  = 0;                           // phase-B aliases over dead XT/nrm/A/U
constexpr size_t H2_O  = H1_O + (size_t)4096*1024;
constexpr size_t H3_O  = H2_O + (size_t)4096*256;     // ends 5,767,167 < H_O

__device__ float g_ws[WS_F];
__device__ int   g_idx[(size_t)BB*NN*KNN];
__device__ int   g_isbf16;                            // runtime input-dtype flag

__device__ __forceinline__ float b2f(bf16 x){ return __bfloat162float(x); }
// dtype-agnostic input load (wave-uniform branch on g_isbf16)
__device__ __forceinline__ float ldi(const void* p, size_t i){
  return g_isbf16 ? b2f(((const bf16*)p)[i]) : ((const float*)p)[i];
}

// ---------------------------------------------------------------- dtype sniffer
// Low 16 bits of each 32-bit word: genuine bf16 randn -> exponent code in [119,129] ~99%;
// fp32 randn -> those bits are uniform mantissa bits -> ~4%. 2048 words of pos (8 KB, safe both worlds).
__global__ __launch_bounds__(256) void k_sniff(const unsigned* __restrict__ posw){
  __shared__ int cnt[256];
  const int tid = threadIdx.x;
  int c = 0;
  for(int k=0;k<8;k++){
    unsigned w = posw[tid*8+k];
    unsigned code = (w & 0x7F80u) >> 7;
    if(code >= 119u && code <= 129u) c++;
  }
  cnt[tid] = c; __syncthreads();
  for(int s=128;s>0;s>>=1){ if(tid<s) cnt[tid]+=cnt[tid+s]; __syncthreads(); }
  if(tid==0) g_isbf16 = (cnt[0] > 1024) ? 1 : 0;
}

// ---------------------------------------------------------------- diagnostic (2B/elem: safe both worlds)
__global__ __launch_bounds__(256) void k_diag(bf16* __restrict__ out, int n, float v){
  int t = blockIdx.x*256 + threadIdx.x;
  if(t < n) out[t] = __float2bfloat16(v);
}

// ---------------------------------------------------------------- prep
__global__ __launch_bounds__(256) void k_prep(const void* __restrict__ pos){
  int t = blockIdx.x*256 + threadIdx.x;            // grid=128 -> t < 32768 exactly
  int b = t >> 11, i = t & (NN-1);
  float x = ldi(pos, (size_t)t*3+0), y = ldi(pos, (size_t)t*3+1), z = ldi(pos, (size_t)t*3+2);
  float* Xb = g_ws + XT_O + (size_t)b*64*NN;
  Xb[0*NN+i] = x; Xb[1*NN+i] = y; Xb[2*NN+i] = z;
  g_ws[NRM_O + t] = x*x + y*y + z*z;
}

// ---------------------------------------------------------------- kNN: 8 query rows/block, top-30 smallest
template<int C>
__global__ __launch_bounds__(256) void k_knn(){
  const int tid = threadIdx.x;
  const int b  = blockIdx.x >> 8;
  const int i0 = (blockIdx.x & 255) * 8;
  __shared__ float xi[8][C];
  __shared__ float nI[8];
  __shared__ float redV[4];
  __shared__ int   redI[4];
  const float* Xb  = g_ws + XT_O + (size_t)b*64*NN;
  const float* nrm = g_ws + NRM_O;
  for(int t = tid; t < 8*C; t += 256){
    int r = t / C, c = t - r*C;
    xi[r][c] = Xb[c*NN + i0 + r];
  }
  if(tid < 8) nI[tid] = nrm[b*NN + i0 + tid];
  __syncthreads();

  float nj[8];
  float dot[8][8];
  #pragma unroll
  for(int s=0;s<8;s++) nj[s] = nrm[b*NN + tid + s*256];
  #pragma unroll
  for(int r=0;r<8;r++){
    #pragma unroll
    for(int s=0;s<8;s++) dot[r][s] = 0.f;
  }
  for(int c=0;c<C;c++){
    float vj[8];
    #pragma unroll
    for(int s=0;s<8;s++) vj[s] = Xb[c*NN + tid + s*256];
    #pragma unroll
    for(int r=0;r<8;r++){
      float xc = xi[r][c];
      #pragma unroll
      for(int s=0;s<8;s++) dot[r][s] = fmaf(xc, vj[s], dot[r][s]);
    }
  }

  #pragma unroll
  for(int r=0;r<8;r++){
    float d[8];
    #pragma unroll
    for(int s=0;s<8;s++) d[s] = fmaf(-2.f, dot[r][s], nI[r] + nj[s]);
    for(int kk=0; kk<KNN; kk++){
      float bv = FLT_MAX; int bi = 1<<30;
      #pragma unroll
      for(int s=0;s<8;s++){                        // ascending s => ascending j; strict < keeps lowest idx on tie
        if(d[s] < bv){ bv = d[s]; bi = tid + (s<<8); }
      }
      #pragma unroll
      for(int off=32; off>0; off>>=1){
        float ov = __shfl_xor(bv, off, 64);
        int   oi = __shfl_xor(bi, off, 64);
        if(ov < bv || (ov == bv && oi < bi)){ bv = ov; bi = oi; }
      }
      if((tid & 63) == 0){ redV[tid>>6] = bv; redI[tid>>6] = bi; }
      __syncthreads();
      float fv = redV[0]; int fi = redI[0];
      #pragma unroll
      for(int wg=1; wg<4; wg++){
        float ov = redV[wg]; int oi = redI[wg];
        if(ov < fv || (ov == fv && oi < fi)){ fv = ov; fi = oi; }
      }
      if(tid == 0) g_idx[((size_t)b*NN + i0 + r)*KNN + kk] = fi;
      if((fi & 255) == tid){
        int s = fi >> 8;
        #pragma unroll
        for(int s2=0;s2<8;s2++) if(s2 == s) d[s2] = FLT_MAX;
      }
      __syncthreads();
    }
  }
}

// ---------------------------------------------------------------- per-point precompute: A = x·(W0a-W0b)+b0, U = x·W0b
template<int C, bool EXTIN>
__global__ __launch_bounds__(256) void k_stage_pre(const void* __restrict__ Xin, int xOff,
    int rowStride, int colOff, const void* __restrict__ W0, const void* __restrict__ b0){
  __shared__ float Wd[C*64];
  __shared__ float Wb[C*64];
  __shared__ float bb[64];
  __shared__ float xs[4][C];
  const int tid = threadIdx.x;
  for(int t=tid; t<C*64; t+=256){
    float top = ldi(W0, t), bot = ldi(W0, (size_t)C*64 + t);
    Wd[t] = top - bot; Wb[t] = bot;
  }
  if(tid < 64) bb[tid] = ldi(b0, tid);
  const int wid = tid >> 6, lane = tid & 63;
  const int point = blockIdx.x*4 + wid;
  if(lane < C){
    float x;
    if(EXTIN) x = ldi(Xin, (size_t)point*rowStride + colOff + lane);
    else      x = g_ws[(size_t)xOff + (size_t)point*rowStride + colOff + lane];
    xs[wid][lane] = x;
  }
  __syncthreads();
  float a = bb[lane], u = 0.f;
  for(int c=0;c<C;c++){
    float xc = xs[wid][c];
    a = fmaf(xc, Wd[c*64 + lane], a);
    u = fmaf(xc, Wb[c*64 + lane], u);
  }
  g_ws[A_O + (size_t)point*64 + lane] = a;
  g_ws[U_O + (size_t)point*64 + lane] = u;
}

// ---------------------------------------------------------------- edge agg: max_k( relu(a_i+u_j) @ W1 + b1 )
template<bool WRITE_NEXT>
__global__ __launch_bounds__(256) void k_edge_agg(const void* __restrict__ W1,
    const void* __restrict__ b1, int colOff){
  __shared__ float hk[4][KNN][64];                     // 30.7 KB
  const int tid = threadIdx.x;
  const int wid = tid >> 6, lane = tid & 63;
  const int point = blockIdx.x*4 + wid;
  const int b = point >> 11, i = point & (NN-1);
  float w[64];
  #pragma unroll
  for(int c=0;c<64;c++) w[c] = ldi(W1, (size_t)c*64 + lane);  // W1 column 'lane' in registers
  const float bias = ldi(b1, lane);
  const float a = g_ws[A_O + (size_t)point*64 + lane];
  const int* ip = g_idx + (size_t)point*KNN;
  const float* Ub = g_ws + U_O + (size_t)b*NN*64;
  for(int kk=0; kk<KNN; kk++){
    int j = ip[kk] & (NN-1);                           // clamp = fault guard
    hk[wid][kk][lane] = fmaxf(a + Ub[(size_t)j*64 + lane], 0.f);
  }
  __syncthreads();
  float acc = -FLT_MAX;
  for(int kk=0; kk<KNN; kk++){
    float v0 = bias, v1 = 0.f, v2 = 0.f, v3 = 0.f;
    #pragma unroll
    for(int c=0;c<64;c+=4){
      float4 hv = *(const float4*)&hk[wid][kk][c];     // wave-broadcast, conflict-free
      v0 = fmaf(hv.x, w[c+0], v0);
      v1 = fmaf(hv.y, w[c+1], v1);
      v2 = fmaf(hv.z, w[c+2], v2);
      v3 = fmaf(hv.w, w[c+3], v3);
    }
    acc = fmaxf(acc, (v0 + v1) + (v2 + v3));
  }
  g_ws[H_O + (size_t)point*192 + colOff + lane] = acc;
  if(WRITE_NEXT){
    g_ws[XT_O + ((size_t)b*64 + lane)*NN + i] = acc;   // transposed copy for next kNN
    __syncthreads();
    hk[wid][0][lane] = acc*acc;
    __syncthreads();
    if(lane == 0){
      float s = 0.f;
      for(int c=0;c<64;c++) s += hk[wid][0][c];
      g_ws[NRM_O + point] = s;
    }
  }
}

// ---------------------------------------------------------------- fp32 GEMM: C = A @ W + bias (opt relu)
template<bool RELU>
__global__ __launch_bounds__(256) void k_gemm(int aOff, const void* __restrict__ W,
    const void* __restrict__ bias, int cOff, int Kd, int Nn){
  __shared__ float As[64][20];
  __shared__ float Bs[16][68];
  const int tid = threadIdx.x;
  const int bm = blockIdx.x, bn = blockIdx.y;
  const int tx = tid & 15, ty = tid >> 4;
  const int ar = tid >> 2, ak = (tid & 3) * 4;
  const int bk = tid >> 4, bnn = (tid & 15) * 4;
  const float* Aa = g_ws + aOff;
  float* Cc = g_ws + cOff;
  float acc[4][4] = {};
  for(int k0 = 0; k0 < Kd; k0 += 16){
    float4 av4 = *(const float4*)(Aa + (size_t)(bm*64 + ar)*Kd + k0 + ak);
    As[ar][ak+0] = av4.x; As[ar][ak+1] = av4.y; As[ar][ak+2] = av4.z; As[ar][ak+3] = av4.w;
    size_t wbase = (size_t)(k0 + bk)*Nn + bn*64 + bnn;
    Bs[bk][bnn+0] = ldi(W, wbase+0); Bs[bk][bnn+1] = ldi(W, wbase+1);
    Bs[bk][bnn+2] = ldi(W, wbase+2); Bs[bk][bnn+3] = ldi(W, wbase+3);
    __syncthreads();
    #pragma unroll
    for(int k=0;k<16;k+=4){
      float4 a4[4], b4[4];
      #pragma unroll
      for(int m=0;m<4;m++) a4[m] = *(const float4*)&As[ty*4+m][k];
      #pragma unroll
      for(int q=0;q<4;q++) b4[q] = *(const float4*)&Bs[k+q][tx*4];
      #pragma unroll
      for(int m=0;m<4;m++){
        #pragma unroll
        for(int q=0;q<4;q++){
          float av = ((const float*)&a4[m])[q];
          acc[m][0] = fmaf(av, b4[q].x, acc[m][0]);
          acc[m][1] = fmaf(av, b4[q].y, acc[m][1]);
          acc[m][2] = fmaf(av, b4[q].z, acc[m][2]);
          acc[m][3] = fmaf(av, b4[q].w, acc[m][3]);
        }
      }
    }
    __syncthreads();
  }
  #pragma unroll
  for(int m=0;m<4;m++){
    int row = bm*64 + ty*4 + m;
    #pragma unroll
    for(int q=0;q<4;q++){
      int col = bn*64 + tx*4 + q;
      float v = acc[m][q] + ldi(bias, col);
      if(RELU) v = fmaxf(v, 0.f);
      Cc[(size_t)row*Nn + col] = v;
    }
  }
}

// ---------------------------------------------------------------- final 128->3, dtype-matched store
__global__ __launch_bounds__(256) void k_final(const void* __restrict__ FW,
    const void* __restrict__ FB, void* __restrict__ out, int outOff){
  __shared__ float wf[128*3];
  __shared__ float bf3[3];
  const int tid = threadIdx.x;
  for(int t=tid; t<384; t+=256) wf[t] = ldi(FW, t);
  if(tid < 3) bf3[tid] = ldi(FB, tid);
  __syncthreads();
  const int p = blockIdx.x*256 + tid;                // < 4096 exactly
  const float* h = g_ws + H3_O + (size_t)p*128;
  float a0 = bf3[0], a1 = bf3[1], a2 = bf3[2];
  #pragma unroll 8
  for(int c=0;c<128;c++){
    float x = h[c];
    a0 = fmaf(x, wf[c*3+0], a0);
    a1 = fmaf(x, wf[c*3+1], a1);
    a2 = fmaf(x, wf[c*3+2], a2);
  }
  size_t o = (size_t)outOff + (size_t)p*3;
  if(g_isbf16){
    bf16* ob = (bf16*)out;
    ob[o+0] = __float2bfloat16(a0); ob[o+1] = __float2bfloat16(a1); ob[o+2] = __float2bfloat16(a2);
  } else {
    float* of = (float*)out;
    of[o+0] = a0; of[o+1] = a1; of[o+2] = a2;
  }
}

extern "C" void kernel_launch(void* const* d_in, const int* in_sizes, int n_in,
                              void* d_out, int out_size, void* d_ws, size_t ws_size,
                              hipStream_t stream){
  (void)d_ws; (void)ws_size;
  static const int EXP[21] = {98304, 384,64, 4096,64, 8192,64, 4096,64, 8192,64, 4096,64,
                              196608,1024, 262144,256, 32768,128, 384,3};
  // ---- verified input mapping; never launch with unverified pointers ----
  const void* in[21];
  int posmatch = 0;
  bool run = false;
  if(n_in == 21){
    for(int e=0; e<21; e++) posmatch += (in_sizes[e] == EXP[e]) ? 1 : 0;
    if(posmatch == 21){
      for(int e=0; e<21; e++) in[e] = d_in[e];
      run = true;
    } else {
      bool used[21] = {false}; const void* m[21]; bool ok = true;
      for(int e=0; e<21 && ok; e++){
        int hit = -1;
        for(int i2=0; i2<21; i2++)
          if(!used[i2] && in_sizes[i2] == EXP[e]){ hit = i2; break; }
        if(hit < 0) ok = false;
        else { used[hit] = true; m[e] = d_in[hit]; }
      }
      if(ok){ for(int e=0; e<21; e++) in[e] = m[e]; run = true; }
    }
  }
  if(!run){
    float V = 1000.f*(float)n_in + 10.f*(float)posmatch;
    k_diag<<<(out_size+255)/256, 256, 0, stream>>>((bf16*)d_out, out_size, V);
    return;
  }
  const void* pos  = in[0];
  const void* c1w0 = in[1];  const void* c1b0 = in[2];
  const void* c1w1 = in[3];  const void* c1b1 = in[4];
  const void* c2w0 = in[5];  const void* c2b0 = in[6];
  const void* c2w1 = in[7];  const void* c2b1 = in[8];
  const void* c3w0 = in[9];  const void* c3b0 = in[10];
  const void* c3w1 = in[11]; const void* c3b1 = in[12];
  const void* mw0  = in[13]; const void* mb0  = in[14];
  const void* mw1  = in[15]; const void* mb1  = in[16];
  const void* mw2  = in[17]; const void* mb2  = in[18];
  const void* fw   = in[19]; const void* fb   = in[20];

  dim3 b256(256);
  k_sniff<<<1, b256, 0, stream>>>((const unsigned*)pos);
  k_prep<<<128, b256, 0, stream>>>(pos);

  // stage 1 (C=3)
  k_knn<3><<<4096, b256, 0, stream>>>();
  k_stage_pre<3,true><<<8192, b256, 0, stream>>>(pos, 0, 3, 0, c1w0, c1b0);
  k_edge_agg<true><<<8192, b256, 0, stream>>>(c1w1, c1b1, 0);

  // stage 2 (C=64)
  k_knn<64><<<4096, b256, 0, stream>>>();
  k_stage_pre<64,false><<<8192, b256, 0, stream>>>(nullptr, (int)H_O, 192, 0, c2w0, c2b0);
  k_edge_agg<true><<<8192, b256, 0, stream>>>(c2w1, c2b1, 64);

  // stage 3 (C=64)
  k_knn<64><<<4096, b256, 0, stream>>>();
  k_stage_pre<64,false><<<8192, b256, 0, stream>>>(nullptr, (int)H_O, 192, 64, c3w0, c3b0);
  k_edge_agg<false><<<8192, b256, 0, stream>>>(c3w1, c3b1, 128);

  // final MLP, chunked M=4096; activations aliased over dead XT/nrm/A/U span
  for(int ch=0; ch<8; ch++){
    int ainOff = (int)(H_O + (size_t)ch*4096*192);
    k_gemm<true ><<<dim3(64,16), b256, 0, stream>>>(ainOff, mw0, mb0, (int)H1_O, 192, 1024);
    k_gemm<true ><<<dim3(64, 4), b256, 0, stream>>>((int)H1_O, mw1, mb1, (int)H2_O, 1024, 256);
    k_gemm<false><<<dim3(64, 2), b256, 0, stream>>>((int)H2_O, mw2, mb2, (int)H3_O, 256, 128);
    k_final<<<16, b256, 0, stream>>>(fw, fb, d_out, ch*4096*3);
  }
}

// Round 7
// 3722.334 us; speedup vs baseline: 1.4676x; 1.4676x over previous
//
#include <hip/hip_runtime.h>
#include <hip/hip_bf16.h>
#include <cfloat>
#include <cstddef>

#define BB 16
#define NN 2048
#define KNN 30

using bf16 = __hip_bfloat16;

// ---- static device scratch ----
constexpr size_t XT_O  = 0;
constexpr size_t NRM_O = XT_O  + (size_t)BB*64*NN;
constexpr size_t A_O   = NRM_O + (size_t)BB*NN;
constexpr size_t U_O   = A_O   + (size_t)BB*NN*64;
constexpr size_t H_O   = U_O   + (size_t)BB*NN*64;
constexpr size_t WS_F  = H_O   + (size_t)BB*NN*192;   // 12,615,680 floats = 50.5 MB
constexpr size_t H1_O  = 0;                           // phase-B aliases over dead XT/nrm/A/U
constexpr size_t H2_O  = H1_O + (size_t)4096*1024;
constexpr size_t H3_O  = H2_O + (size_t)4096*256;     // ends 5,767,167 < H_O

__device__ float g_ws[WS_F];
__device__ int   g_idx[(size_t)BB*NN*KNN];
__device__ int   g_isbf16;                            // runtime input-dtype flag (measured: fp32 world)

__device__ __forceinline__ float b2f(bf16 x){ return __bfloat162float(x); }
__device__ __forceinline__ float ldi(const void* p, size_t i){
  return g_isbf16 ? b2f(((const bf16*)p)[i]) : ((const float*)p)[i];
}

// ---------------------------------------------------------------- dtype sniffer (kept: proved fp32; cheap)
__global__ __launch_bounds__(256) void k_sniff(const unsigned* __restrict__ posw){
  __shared__ int cnt[256];
  const int tid = threadIdx.x;
  int c = 0;
  for(int k=0;k<8;k++){
    unsigned w = posw[tid*8+k];
    unsigned code = (w & 0x7F80u) >> 7;
    if(code >= 119u && code <= 129u) c++;
  }
  cnt[tid] = c; __syncthreads();
  for(int s=128;s>0;s>>=1){ if(tid<s) cnt[tid]+=cnt[tid+s]; __syncthreads(); }
  if(tid==0) g_isbf16 = (cnt[0] > 1024) ? 1 : 0;
}

// ---------------------------------------------------------------- diagnostic
__global__ __launch_bounds__(256) void k_diag(bf16* __restrict__ out, int n, float v){
  int t = blockIdx.x*256 + threadIdx.x;
  if(t < n) out[t] = __float2bfloat16(v);
}

// ---------------------------------------------------------------- prep
__global__ __launch_bounds__(256) void k_prep(const void* __restrict__ pos){
  int t = blockIdx.x*256 + threadIdx.x;            // grid=128 -> t < 32768 exactly
  int b = t >> 11, i = t & (NN-1);
  float x = ldi(pos, (size_t)t*3+0), y = ldi(pos, (size_t)t*3+1), z = ldi(pos, (size_t)t*3+2);
  float* Xb = g_ws + XT_O + (size_t)b*64*NN;
  Xb[0*NN+i] = x; Xb[1*NN+i] = y; Xb[2*NN+i] = z;
  g_ws[NRM_O + t] = x*x + y*y + z*z;
}

// ---------------------------------------------------------------- kNN: 4 rows/block; barrier-free wave-local top-30
// Phase 1: cooperative distance compute (vj reused across 4 rows). Phase 2: LDS transpose.
// Phase 3: wave w selects row w privately — no barriers in the 30-iter loop.
template<int C>
__global__ __launch_bounds__(256) void k_knn(){
  const int tid  = threadIdx.x;
  const int wid  = tid >> 6, lane = tid & 63;
  const int b    = blockIdx.x >> 9;                // 512 blocks per batch
  const int i0   = (blockIdx.x & 511) * 4;         // 4 query rows
  __shared__ float dlds[4][NN];                    // 32 KB
  __shared__ float xi[4][C];
  __shared__ float nI[4];
  const float* Xb  = g_ws + XT_O + (size_t)b*64*NN;
  const float* nrm = g_ws + NRM_O;
  for(int t = tid; t < 4*C; t += 256){
    int r = t / C, c = t - r*C;
    xi[r][c] = Xb[c*NN + i0 + r];
  }
  if(tid < 4) nI[tid] = nrm[b*NN + i0 + tid];
  __syncthreads();

  float nj[8];
  float dot[4][8];
  #pragma unroll
  for(int s=0;s<8;s++) nj[s] = nrm[b*NN + tid + s*256];
  #pragma unroll
  for(int r=0;r<4;r++){
    #pragma unroll
    for(int s=0;s<8;s++) dot[r][s] = 0.f;
  }
  for(int c=0;c<C;c++){
    float vj[8];
    #pragma unroll
    for(int s=0;s<8;s++) vj[s] = Xb[c*NN + tid + s*256];   // coalesced; reused by 4 rows
    #pragma unroll
    for(int r=0;r<4;r++){
      float xc = xi[r][c];
      #pragma unroll
      for(int s=0;s<8;s++) dot[r][s] = fmaf(xc, vj[s], dot[r][s]);
    }
  }
  #pragma unroll
  for(int r=0;r<4;r++){
    float nIr = nI[r];
    #pragma unroll
    for(int s=0;s<8;s++) dlds[r][tid + s*256] = fmaf(-2.f, dot[r][s], nIr + nj[s]);
  }
  __syncthreads();

  // wave 'wid' owns row 'wid': lane holds j = lane + 64*q, q in [0,32)
  float v[32];
  #pragma unroll
  for(int q=0;q<32;q++) v[q] = dlds[wid][lane + (q<<6)];
  const size_t rowbase = ((size_t)b*NN + i0 + wid)*KNN;
  for(int kk=0; kk<KNN; kk++){
    float bv = v[0]; int bq = 0;
    #pragma unroll
    for(int q=1;q<32;q++){ if(v[q] < bv){ bv = v[q]; bq = q; } }   // strict < -> lowest q (lowest j) on tie
    int bj = lane + (bq<<6);
    #pragma unroll
    for(int off=32; off>0; off>>=1){
      float ov = __shfl_xor(bv, off, 64);
      int   oj = __shfl_xor(bj, off, 64);
      if(ov < bv || (ov == bv && oj < bj)){ bv = ov; bj = oj; }
    }
    if(lane == 0) g_idx[rowbase + kk] = bj;
    if((bj & 63) == lane){
      int kq = bj >> 6;
      #pragma unroll
      for(int q=0;q<32;q++) if(q == kq) v[q] = FLT_MAX;
    }
  }
}

// ---------------------------------------------------------------- per-point precompute: A = x·(W0a-W0b)+b0, U = x·W0b
template<int C, bool EXTIN>
__global__ __launch_bounds__(256) void k_stage_pre(const void* __restrict__ Xin, int xOff,
    int rowStride, int colOff, const void* __restrict__ W0, const void* __restrict__ b0){
  __shared__ float Wd[C*64];
  __shared__ float Wb[C*64];
  __shared__ float bb[64];
  __shared__ float xs[4][C];
  const int tid = threadIdx.x;
  for(int t=tid; t<C*64; t+=256){
    float top = ldi(W0, t), bot = ldi(W0, (size_t)C*64 + t);
    Wd[t] = top - bot; Wb[t] = bot;
  }
  if(tid < 64) bb[tid] = ldi(b0, tid);
  const int wid = tid >> 6, lane = tid & 63;
  const int point = blockIdx.x*4 + wid;
  if(lane < C){
    float x;
    if(EXTIN) x = ldi(Xin, (size_t)point*rowStride + colOff + lane);
    else      x = g_ws[(size_t)xOff + (size_t)point*rowStride + colOff + lane];
    xs[wid][lane] = x;
  }
  __syncthreads();
  float a = bb[lane], u = 0.f;
  for(int c=0;c<C;c++){
    float xc = xs[wid][c];
    a = fmaf(xc, Wd[c*64 + lane], a);
    u = fmaf(xc, Wb[c*64 + lane], u);
  }
  g_ws[A_O + (size_t)point*64 + lane] = a;
  g_ws[U_O + (size_t)point*64 + lane] = u;
}

// ---------------------------------------------------------------- edge agg: max_k( relu(a_i+u_j) @ W1 + b1 )
// 16 points/block (4 per wave, sequential) to amortize W1 register load 4x
template<bool WRITE_NEXT>
__global__ __launch_bounds__(256) void k_edge_agg(const void* __restrict__ W1,
    const void* __restrict__ b1, int colOff){
  __shared__ float hk[4][KNN][64];                     // 30.7 KB, wave-private slices
  const int tid = threadIdx.x;
  const int wid = tid >> 6, lane = tid & 63;
  float w[64];
  #pragma unroll
  for(int c=0;c<64;c++) w[c] = ldi(W1, (size_t)c*64 + lane);  // W1 column 'lane'
  const float bias = ldi(b1, lane);
  for(int pp=0; pp<4; pp++){
    const int point = blockIdx.x*16 + wid*4 + pp;
    const int b = point >> 11, i = point & (NN-1);
    const float a = g_ws[A_O + (size_t)point*64 + lane];
    const int* ip = g_idx + (size_t)point*KNN;
    const float* Ub = g_ws + U_O + (size_t)b*NN*64;
    for(int kk=0; kk<KNN; kk++){
      int j = ip[kk] & (NN-1);                         // clamp = fault guard
      hk[wid][kk][lane] = fmaxf(a + Ub[(size_t)j*64 + lane], 0.f);
    }
    __syncthreads();
    float acc = -FLT_MAX;
    for(int kk=0; kk<KNN; kk++){
      float v0 = bias, v1 = 0.f, v2 = 0.f, v3 = 0.f;
      #pragma unroll
      for(int c=0;c<64;c+=4){
        float4 hv = *(const float4*)&hk[wid][kk][c];   // wave-broadcast, conflict-free
        v0 = fmaf(hv.x, w[c+0], v0);
        v1 = fmaf(hv.y, w[c+1], v1);
        v2 = fmaf(hv.z, w[c+2], v2);
        v3 = fmaf(hv.w, w[c+3], v3);
      }
      acc = fmaxf(acc, (v0 + v1) + (v2 + v3));
    }
    g_ws[H_O + (size_t)point*192 + colOff + lane] = acc;
    if(WRITE_NEXT){
      g_ws[XT_O + ((size_t)b*64 + lane)*NN + i] = acc; // transposed copy for next kNN
      float sq = acc*acc;
      #pragma unroll
      for(int off=32; off>0; off>>=1) sq += __shfl_xor(sq, off, 64);
      if(lane == 0) g_ws[NRM_O + point] = sq;
    }
    __syncthreads();                                   // protect hk before next pp
  }
}

// ---------------------------------------------------------------- fp32 GEMM: C = A @ W + bias (opt relu)
template<bool RELU>
__global__ __launch_bounds__(256) void k_gemm(int aOff, const void* __restrict__ W,
    const void* __restrict__ bias, int cOff, int Kd, int Nn){
  __shared__ float As[64][20];
  __shared__ float Bs[16][68];
  const int tid = threadIdx.x;
  const int bm = blockIdx.x, bn = blockIdx.y;
  const int tx = tid & 15, ty = tid >> 4;
  const int ar = tid >> 2, ak = (tid & 3) * 4;
  const int bk = tid >> 4, bnn = (tid & 15) * 4;
  const float* Aa = g_ws + aOff;
  float* Cc = g_ws + cOff;
  float acc[4][4] = {};
  for(int k0 = 0; k0 < Kd; k0 += 16){
    float4 av4 = *(const float4*)(Aa + (size_t)(bm*64 + ar)*Kd + k0 + ak);
    As[ar][ak+0] = av4.x; As[ar][ak+1] = av4.y; As[ar][ak+2] = av4.z; As[ar][ak+3] = av4.w;
    size_t wbase = (size_t)(k0 + bk)*Nn + bn*64 + bnn;
    Bs[bk][bnn+0] = ldi(W, wbase+0); Bs[bk][bnn+1] = ldi(W, wbase+1);
    Bs[bk][bnn+2] = ldi(W, wbase+2); Bs[bk][bnn+3] = ldi(W, wbase+3);
    __syncthreads();
    #pragma unroll
    for(int k=0;k<16;k+=4){
      float4 a4[4], b4[4];
      #pragma unroll
      for(int m=0;m<4;m++) a4[m] = *(const float4*)&As[ty*4+m][k];
      #pragma unroll
      for(int q=0;q<4;q++) b4[q] = *(const float4*)&Bs[k+q][tx*4];
      #pragma unroll
      for(int m=0;m<4;m++){
        #pragma unroll
        for(int q=0;q<4;q++){
          float av = ((const float*)&a4[m])[q];
          acc[m][0] = fmaf(av, b4[q].x, acc[m][0]);
          acc[m][1] = fmaf(av, b4[q].y, acc[m][1]);
          acc[m][2] = fmaf(av, b4[q].z, acc[m][2]);
          acc[m][3] = fmaf(av, b4[q].w, acc[m][3]);
        }
      }
    }
    __syncthreads();
  }
  #pragma unroll
  for(int m=0;m<4;m++){
    int row = bm*64 + ty*4 + m;
    #pragma unroll
    for(int q=0;q<4;q++){
      int col = bn*64 + tx*4 + q;
      float v = acc[m][q] + ldi(bias, col);
      if(RELU) v = fmaxf(v, 0.f);
      Cc[(size_t)row*Nn + col] = v;
    }
  }
}

// ---------------------------------------------------------------- final 128->3, dtype-matched store
__global__ __launch_bounds__(256) void k_final(const void* __restrict__ FW,
    const void* __restrict__ FB, void* __restrict__ out, int outOff){
  __shared__ float wf[128*3];
  __shared__ float bf3[3];
  const int tid = threadIdx.x;
  for(int t=tid; t<384; t+=256) wf[t] = ldi(FW, t);
  if(tid < 3) bf3[tid] = ldi(FB, tid);
  __syncthreads();
  const int p = blockIdx.x*256 + tid;                // < 4096 exactly
  const float* h = g_ws + H3_O + (size_t)p*128;
  float a0 = bf3[0], a1 = bf3[1], a2 = bf3[2];
  #pragma unroll 8
  for(int c=0;c<128;c++){
    float x = h[c];
    a0 = fmaf(x, wf[c*3+0], a0);
    a1 = fmaf(x, wf[c*3+1], a1);
    a2 = fmaf(x, wf[c*3+2], a2);
  }
  size_t o = (size_t)outOff + (size_t)p*3;
  if(g_isbf16){
    bf16* ob = (bf16*)out;
    ob[o+0] = __float2bfloat16(a0); ob[o+1] = __float2bfloat16(a1); ob[o+2] = __float2bfloat16(a2);
  } else {
    float* of = (float*)out;
    of[o+0] = a0; of[o+1] = a1; of[o+2] = a2;
  }
}

extern "C" void kernel_launch(void* const* d_in, const int* in_sizes, int n_in,
                              void* d_out, int out_size, void* d_ws, size_t ws_size,
                              hipStream_t stream){
  (void)d_ws; (void)ws_size;
  static const int EXP[21] = {98304, 384,64, 4096,64, 8192,64, 4096,64, 8192,64, 4096,64,
                              196608,1024, 262144,256, 32768,128, 384,3};
  const void* in[21];
  int posmatch = 0;
  bool run = false;
  if(n_in == 21){
    for(int e=0; e<21; e++) posmatch += (in_sizes[e] == EXP[e]) ? 1 : 0;
    if(posmatch == 21){
      for(int e=0; e<21; e++) in[e] = d_in[e];
      run = true;
    } else {
      bool used[21] = {false}; const void* m[21]; bool ok = true;
      for(int e=0; e<21 && ok; e++){
        int hit = -1;
        for(int i2=0; i2<21; i2++)
          if(!used[i2] && in_sizes[i2] == EXP[e]){ hit = i2; break; }
        if(hit < 0) ok = false;
        else { used[hit] = true; m[e] = d_in[hit]; }
      }
      if(ok){ for(int e=0; e<21; e++) in[e] = m[e]; run = true; }
    }
  }
  if(!run){
    float V = 1000.f*(float)n_in + 10.f*(float)posmatch;
    k_diag<<<(out_size+255)/256, 256, 0, stream>>>((bf16*)d_out, out_size, V);
    return;
  }
  const void* pos  = in[0];
  const void* c1w0 = in[1];  const void* c1b0 = in[2];
  const void* c1w1 = in[3];  const void* c1b1 = in[4];
  const void* c2w0 = in[5];  const void* c2b0 = in[6];
  const void* c2w1 = in[7];  const void* c2b1 = in[8];
  const void* c3w0 = in[9];  const void* c3b0 = in[10];
  const void* c3w1 = in[11]; const void* c3b1 = in[12];
  const void* mw0  = in[13]; const void* mb0  = in[14];
  const void* mw1  = in[15]; const void* mb1  = in[16];
  const void* mw2  = in[17]; const void* mb2  = in[18];
  const void* fw   = in[19]; const void* fb   = in[20];

  dim3 b256(256);
  k_sniff<<<1, b256, 0, stream>>>((const unsigned*)pos);
  k_prep<<<128, b256, 0, stream>>>(pos);

  // stage 1 (C=3)
  k_knn<3><<<8192, b256, 0, stream>>>();
  k_stage_pre<3,true><<<8192, b256, 0, stream>>>(pos, 0, 3, 0, c1w0, c1b0);
  k_edge_agg<true><<<2048, b256, 0, stream>>>(c1w1, c1b1, 0);

  // stage 2 (C=64)
  k_knn<64><<<8192, b256, 0, stream>>>();
  k_stage_pre<64,false><<<8192, b256, 0, stream>>>(nullptr, (int)H_O, 192, 0, c2w0, c2b0);
  k_edge_agg<true><<<2048, b256, 0, stream>>>(c2w1, c2b1, 64);

  // stage 3 (C=64)
  k_knn<64><<<8192, b256, 0, stream>>>();
  k_stage_pre<64,false><<<8192, b256, 0, stream>>>(nullptr, (int)H_O, 192, 64, c3w0, c3b0);
  k_edge_agg<false><<<2048, b256, 0, stream>>>(c3w1, c3b1, 128);

  // final MLP, chunked M=4096; activations aliased over dead XT/nrm/A/U span
  for(int ch=0; ch<8; ch++){
    int ainOff = (int)(H_O + (size_t)ch*4096*192);
    k_gemm<true ><<<dim3(64,16), b256, 0, stream>>>(ainOff, mw0, mb0, (int)H1_O, 192, 1024);
    k_gemm<true ><<<dim3(64, 4), b256, 0, stream>>>((int)H1_O, mw1, mb1, (int)H2_O, 1024, 256);
    k_gemm<false><<<dim3(64, 2), b256, 0, stream>>>((int)H2_O, mw2, mb2, (int)H3_O, 256, 128);
    k_final<<<16, b256, 0, stream>>>(fw, fb, d_out, ch*4096*3);
  }
}